// Round 1
// baseline (460.741 us; speedup 1.0000x reference)
//
#include <hip/hip_runtime.h>
#include <stdint.h>

// Problem constants
constexpr int SEQ   = 2048;
constexpr int NHEAD = 16;
constexpr int HDSZ  = 128;   // head dim
constexpr int HDIM  = 2048;  // model dim
constexpr float QK_SCALE = 0.08838834764831845f; // 1/sqrt(128)

typedef __attribute__((ext_vector_type(8))) __bf16 bf16x8;
typedef __attribute__((ext_vector_type(4))) __bf16 bf16x4;
typedef __attribute__((ext_vector_type(8))) short  short8;
typedef __attribute__((ext_vector_type(4))) float  f32x4;

__device__ __forceinline__ void gl_lds16(const void* gptr, void* lptr) {
  // async global->LDS, 16B/lane; LDS dst is wave-uniform base + lane*16
  __builtin_amdgcn_global_load_lds(
      (const __attribute__((address_space(1))) unsigned int*)gptr,
      (__attribute__((address_space(3))) unsigned int*)lptr, 16, 0, 0);
}

// ---------------- fp32 -> bf16 cast (vectorized) ----------------
__global__ __launch_bounds__(256) void cast_f32_bf16(
    const float* __restrict__ in, __bf16* __restrict__ out, int n4) {
  int i = blockIdx.x * blockDim.x + threadIdx.x;
  int stride = gridDim.x * blockDim.x;
  for (; i < n4; i += stride) {
    float4 v = ((const float4*)in)[i];
    bf16x4 o = { (__bf16)v.x, (__bf16)v.y, (__bf16)v.z, (__bf16)v.w };
    ((bf16x4*)out)[i] = o;
  }
}

// ---------------- NT GEMM: C[M,N] = A[M,K] * B[N,K]^T ----------------
// m97 structure: 128x128 tile, BK=32, 4 waves, global_load_lds(16B) staging.
// MODE 0: bf16 out scattered to [b, h, s, d] (QKV). MODE 1: fp32 row-major.
template <int MODE>
__global__ __launch_bounds__(256) void gemm_bt(
    const __bf16* __restrict__ A, const __bf16* __restrict__ B,
    void* __restrict__ C, int M, int N, int K) {
  __shared__ __bf16 As[128 * 32];
  __shared__ __bf16 Bs[128 * 32];
  const int tid  = threadIdx.x;
  const int lane = tid & 63;
  const int w    = tid >> 6;
  const int lg   = lane >> 4, lr = lane & 15;
  const int wr   = w >> 1, wc = w & 1;
  const long mbase = (long)blockIdx.y * 128;
  const long nbase = (long)blockIdx.x * 128;

  f32x4 acc[4][4];
#pragma unroll
  for (int i = 0; i < 4; ++i)
#pragma unroll
    for (int j = 0; j < 4; ++j) acc[i][j] = (f32x4){0.f, 0.f, 0.f, 0.f};

  const int srow = lane >> 2;       // row within 16-row staging chunk
  const int scol = (lane & 3) * 8;  // bf16 elem offset (16B granules)

  for (int kt = 0; kt < K; kt += 32) {
#pragma unroll
    for (int i = 0; i < 2; ++i) {
      const int c = w * 2 + i;  // 8 chunks of 16 rows x 32 k each
      gl_lds16(A + (mbase + c * 16 + srow) * (long)K + kt + scol, &As[c * 512]);
      gl_lds16(B + (nbase + c * 16 + srow) * (long)K + kt + scol, &Bs[c * 512]);
    }
    __syncthreads();
    bf16x8 af[4], bfv[4];
#pragma unroll
    for (int mm = 0; mm < 4; ++mm)
      af[mm] = *(const bf16x8*)&As[(wr * 64 + mm * 16 + lr) * 32 + lg * 8];
#pragma unroll
    for (int nn = 0; nn < 4; ++nn)
      bfv[nn] = *(const bf16x8*)&Bs[(wc * 64 + nn * 16 + lr) * 32 + lg * 8];
#pragma unroll
    for (int nn = 0; nn < 4; ++nn)
#pragma unroll
      for (int mm = 0; mm < 4; ++mm)
        acc[mm][nn] = __builtin_amdgcn_mfma_f32_16x16x32_bf16(
            af[mm], bfv[nn], acc[mm][nn], 0, 0, 0);
    __syncthreads();
  }

  // Epilogue. D layout (m89-verified): col = lane&15, row = (lane>>4)*4 + r
#pragma unroll
  for (int mm = 0; mm < 4; ++mm) {
#pragma unroll
    for (int nn = 0; nn < 4; ++nn) {
      const long n = nbase + wc * 64 + nn * 16 + lr;
#pragma unroll
      for (int r = 0; r < 4; ++r) {
        const long m = mbase + wr * 64 + mm * 16 + lg * 4 + r;
        if (MODE == 0) {
          const long b = m >> 11, s = m & 2047;
          const long h = n >> 7,  d = n & 127;
          ((__bf16*)C)[((b * NHEAD + h) * SEQ + s) * HDSZ + d] =
              (__bf16)acc[mm][nn][r];
        } else {
          ((float*)C)[m * (long)N + n] = acc[mm][nn][r];
        }
      }
    }
  }
}

// ---------------- fused flash attention ----------------
// grid: (SEQ/64, B*NHEAD); 4 waves; each wave owns 16 q-rows.
// Q hoisted to regs; K staged reg->LDS ([64][136] pad kills 16-way conflict);
// V staged transposed ([128][72]); mask tile via global_load_lds.
__global__ __launch_bounds__(256) void attn_fused(
    const __bf16* __restrict__ Q, const __bf16* __restrict__ K,
    const __bf16* __restrict__ V, const float* __restrict__ mask,
    __bf16* __restrict__ Out) {
  __shared__ __bf16 Ks[64 * 136];  // [kcol][d], ld=136
  __shared__ __bf16 Vt[128 * 72];  // [d][kcol], ld=72
  __shared__ __bf16 Ps[64 * 72];   // [qrow][kcol], ld=72
  __shared__ float  Ms[64 * 64];   // mask tile fp32

  const int tid  = threadIdx.x;
  const int lane = tid & 63;
  const int w    = tid >> 6;
  const int lg   = lane >> 4, lr = lane & 15;
  const int bh   = blockIdx.y;        // b*NHEAD + h
  const int b    = bh >> 4, h = bh & 15;
  const int q0   = blockIdx.x * 64;

  const __bf16* Qh = Q + (size_t)bh * SEQ * HDSZ;
  const __bf16* Kh = K + (size_t)bh * SEQ * HDSZ;
  const __bf16* Vh = V + (size_t)bh * SEQ * HDSZ;
  const float*  Mb = mask + (size_t)b * SEQ * SEQ;

  // Q fragments for this wave's 16 rows (A-operand: row=lr, k=lg*8+i)
  bf16x8 qf[4];
  {
    const int qrow = q0 + w * 16 + lr;
#pragma unroll
    for (int kk = 0; kk < 4; ++kk)
      qf[kk] = *(const bf16x8*)(Qh + (size_t)qrow * HDSZ + kk * 32 + lg * 8);
  }

  float mrow[4], lrow[4];
#pragma unroll
  for (int r = 0; r < 4; ++r) { mrow[r] = -1e30f; lrow[r] = 0.f; }
  f32x4 acco[8];
#pragma unroll
  for (int n = 0; n < 8; ++n) acco[n] = (f32x4){0.f, 0.f, 0.f, 0.f};

  for (int kt = 0; kt < SEQ; kt += 64) {
    // --- stage K tile [64][128] -> Ks [64][136] (reg->LDS, b128) ---
#pragma unroll
    for (int i = 0; i < 4; ++i) {
      const int ch = i * 256 + tid;         // 1024 chunks of 16B
      const int row = ch >> 4, c8 = (ch & 15) * 8;
      uint4 kv = *(const uint4*)(Kh + (size_t)(kt + row) * HDSZ + c8);
      *(uint4*)&Ks[row * 136 + c8] = kv;
    }
    // --- stage V transposed -> Vt [128][72] (packed pair writes) ---
    {
      const int sp = tid & 31;   // s-pair
      const int dc = tid >> 5;   // d chunk 0..7
#pragma unroll
      for (int i = 0; i < 2; ++i) {
        const int d0 = (dc + i * 8) * 8;
        short8 va = *(const short8*)(Vh + (size_t)(kt + 2 * sp) * HDSZ + d0);
        short8 vb = *(const short8*)(Vh + (size_t)(kt + 2 * sp + 1) * HDSZ + d0);
#pragma unroll
        for (int j = 0; j < 8; ++j) {
          unsigned int pk = (unsigned short)va[j] |
                            ((unsigned int)(unsigned short)vb[j] << 16);
          *(unsigned int*)&Vt[(d0 + j) * 72 + 2 * sp] = pk;
        }
      }
    }
    // --- stage mask tile [64][64] f32 via global_load_lds ---
#pragma unroll
    for (int i = 0; i < 4; ++i) {
      const int c = w * 4 + i;
      gl_lds16(Mb + (size_t)(q0 + c * 4 + lg) * SEQ + kt + lr * 4, &Ms[c * 256]);
    }
    __syncthreads();

    // --- S = Q K^T (per wave: 16 rows x 64 cols) ---
    f32x4 sacc[4];
#pragma unroll
    for (int n = 0; n < 4; ++n) sacc[n] = (f32x4){0.f, 0.f, 0.f, 0.f};
#pragma unroll
    for (int n = 0; n < 4; ++n)
#pragma unroll
      for (int kk = 0; kk < 4; ++kk) {
        bf16x8 kf = *(const bf16x8*)&Ks[(n * 16 + lr) * 136 + kk * 32 + lg * 8];
        sacc[n] = __builtin_amdgcn_mfma_f32_16x16x32_bf16(qf[kk], kf, sacc[n], 0, 0, 0);
      }

    // --- online softmax (rows = w*16 + lg*4 + r, cols across lr lanes) ---
    float sv[4][4], tmax[4];
#pragma unroll
    for (int r = 0; r < 4; ++r) tmax[r] = -1e30f;
    const int mrb = w * 16 + lg * 4;
#pragma unroll
    for (int n = 0; n < 4; ++n)
#pragma unroll
      for (int r = 0; r < 4; ++r) {
        float x = sacc[n][r] * QK_SCALE + Ms[(mrb + r) * 64 + n * 16 + lr];
        sv[n][r] = x;
        tmax[r] = fmaxf(tmax[r], x);
      }
#pragma unroll
    for (int r = 0; r < 4; ++r)
#pragma unroll
      for (int off = 1; off < 16; off <<= 1)
        tmax[r] = fmaxf(tmax[r], __shfl_xor(tmax[r], off));
    float corr[4];
#pragma unroll
    for (int r = 0; r < 4; ++r) {
      float mn = fmaxf(mrow[r], tmax[r]);
      corr[r] = __expf(mrow[r] - mn);
      mrow[r] = mn;
    }
    float lsum[4] = {0.f, 0.f, 0.f, 0.f};
#pragma unroll
    for (int n = 0; n < 4; ++n)
#pragma unroll
      for (int r = 0; r < 4; ++r) {
        float p = __expf(sv[n][r] - mrow[r]);
        sv[n][r] = p;
        lsum[r] += p;
      }
#pragma unroll
    for (int r = 0; r < 4; ++r) {
#pragma unroll
      for (int off = 1; off < 16; off <<= 1) lsum[r] += __shfl_xor(lsum[r], off);
      lrow[r] = lrow[r] * corr[r] + lsum[r];
    }
#pragma unroll
    for (int n = 0; n < 8; ++n)
#pragma unroll
      for (int r = 0; r < 4; ++r) acco[n][r] *= corr[r];

    // --- write P (bf16) to LDS; wave-local so no barrier, just lgkm drain ---
#pragma unroll
    for (int n = 0; n < 4; ++n)
#pragma unroll
      for (int r = 0; r < 4; ++r)
        Ps[(w * 16 + lg * 4 + r) * 72 + n * 16 + lr] = (__bf16)sv[n][r];
    __asm__ volatile("s_waitcnt lgkmcnt(0)" ::: "memory");

    // --- O += P V ---
#pragma unroll
    for (int kk = 0; kk < 2; ++kk) {
      bf16x8 pa = *(const bf16x8*)&Ps[(w * 16 + lr) * 72 + kk * 32 + lg * 8];
#pragma unroll
      for (int n = 0; n < 8; ++n) {
        bf16x8 vf = *(const bf16x8*)&Vt[(n * 16 + lr) * 72 + kk * 32 + lg * 8];
        acco[n] = __builtin_amdgcn_mfma_f32_16x16x32_bf16(pa, vf, acco[n], 0, 0, 0);
      }
    }
    __syncthreads();  // protect Ks/Vt/Ms for next tile's staging
  }

  // --- epilogue: normalize, write attn out as [b, s, h*128+d] bf16 ---
#pragma unroll
  for (int r = 0; r < 4; ++r) {
    const float inv = 1.0f / lrow[r];
    const int srow = q0 + w * 16 + lg * 4 + r;
    const size_t base = ((size_t)b * SEQ + srow) * HDIM + h * HDSZ;
#pragma unroll
    for (int n = 0; n < 8; ++n)
      Out[base + n * 16 + lr] = (__bf16)(acco[n][r] * inv);
  }
}

// ---------------- launcher ----------------
extern "C" void kernel_launch(void* const* d_in, const int* in_sizes, int n_in,
                              void* d_out, int out_size, void* d_ws, size_t ws_size,
                              hipStream_t stream) {
  const float* x    = (const float*)d_in[0];
  const float* mask = (const float*)d_in[1];
  const float* wq   = (const float*)d_in[2];
  const float* wk   = (const float*)d_in[3];
  const float* wv   = (const float*)d_in[4];
  const float* wo   = (const float*)d_in[5];

  constexpr long XN = 4096L * 2048;  // 8388608
  constexpr long WN = 2048L * 2048;  // 4194304

  __bf16* xbf = (__bf16*)d_ws;       // also reused as attention output buffer
  __bf16* wqb = xbf + XN;
  __bf16* wkb = wqb + WN;
  __bf16* wvb = wkb + WN;
  __bf16* wob = wvb + WN;
  __bf16* qw  = wob + WN;
  __bf16* kw  = qw + XN;
  __bf16* vw  = kw + XN;
  __bf16* aw  = vw + XN;             // attention output [4096][2048]

  cast_f32_bf16<<<2048, 256, 0, stream>>>(x,  xbf, (int)(XN / 4));
  cast_f32_bf16<<<1024, 256, 0, stream>>>(wq, wqb, (int)(WN / 4));
  cast_f32_bf16<<<1024, 256, 0, stream>>>(wk, wkb, (int)(WN / 4));
  cast_f32_bf16<<<1024, 256, 0, stream>>>(wv, wvb, (int)(WN / 4));
  cast_f32_bf16<<<1024, 256, 0, stream>>>(wo, wob, (int)(WN / 4));

  dim3 gg(2048 / 128, 4096 / 128);  // (N-tiles, M-tiles)
  gemm_bt<0><<<gg, 256, 0, stream>>>(xbf, wqb, qw, 4096, 2048, 2048);
  gemm_bt<0><<<gg, 256, 0, stream>>>(xbf, wkb, kw, 4096, 2048, 2048);
  gemm_bt<0><<<gg, 256, 0, stream>>>(xbf, wvb, vw, 4096, 2048, 2048);

  attn_fused<<<dim3(SEQ / 64, 2 * NHEAD), 256, 0, stream>>>(qw, kw, vw, mask, aw);

  gemm_bt<1><<<gg, 256, 0, stream>>>(aw, wob, d_out, 4096, 2048, 2048);
}

// Round 2
// 415.851 us; speedup vs baseline: 1.1079x; 1.1079x over previous
//
#include <hip/hip_runtime.h>
#include <stdint.h>

// Problem constants
constexpr int SEQ   = 2048;
constexpr int NHEAD = 16;
constexpr int HDSZ  = 128;   // head dim
constexpr int HDIM  = 2048;  // model dim
constexpr float QK_SCALE = 0.08838834764831845f; // 1/sqrt(128)

typedef __attribute__((ext_vector_type(8))) __bf16 bf16x8;
typedef __attribute__((ext_vector_type(4))) __bf16 bf16x4;
typedef __attribute__((ext_vector_type(4))) float  f32x4;

__device__ __forceinline__ void gl_lds16(const void* gptr, void* lptr) {
  // async global->LDS, 16B/lane; LDS dst is wave-uniform base + lane*16
  __builtin_amdgcn_global_load_lds(
      (const __attribute__((address_space(1))) unsigned int*)gptr,
      (__attribute__((address_space(3))) unsigned int*)lptr, 16, 0, 0);
}

// ---------------- fp32 -> bf16 cast (vectorized) ----------------
__global__ __launch_bounds__(256) void cast_f32_bf16(
    const float* __restrict__ in, __bf16* __restrict__ out, int n4) {
  int i = blockIdx.x * blockDim.x + threadIdx.x;
  int stride = gridDim.x * blockDim.x;
  for (; i < n4; i += stride) {
    float4 v = ((const float4*)in)[i];
    bf16x4 o = { (__bf16)v.x, (__bf16)v.y, (__bf16)v.z, (__bf16)v.w };
    ((bf16x4*)out)[i] = o;
  }
}

// ---------------- NT GEMM: C[M,N] = A[M,K] * B[N,K]^T ----------------
// m97 structure: 128x128 tile, BK=32, 4 waves, global_load_lds(16B) staging.
// MODE 0: bf16 out scattered to [b, h, s, d] (Q,K).
// MODE 1: fp32 row-major (final output).
// MODE 2: bf16 out TRANSPOSED to [b, h, d, s] (V) via LDS tile transpose.
template <int MODE>
__global__ __launch_bounds__(256) void gemm_bt(
    const __bf16* __restrict__ A, const __bf16* __restrict__ B,
    void* __restrict__ C, int M, int N, int K) {
  __shared__ __bf16 As[128 * 32];
  __shared__ __bf16 Bs[128 * 32];
  const int tid  = threadIdx.x;
  const int lane = tid & 63;
  const int w    = tid >> 6;
  const int lg   = lane >> 4, lr = lane & 15;
  const int wr   = w >> 1, wc = w & 1;
  const long mbase = (long)blockIdx.y * 128;
  const long nbase = (long)blockIdx.x * 128;

  f32x4 acc[4][4];
#pragma unroll
  for (int i = 0; i < 4; ++i)
#pragma unroll
    for (int j = 0; j < 4; ++j) acc[i][j] = (f32x4){0.f, 0.f, 0.f, 0.f};

  const int srow = lane >> 2;       // row within 16-row staging chunk
  const int scol = (lane & 3) * 8;  // bf16 elem offset (16B granules)

  for (int kt = 0; kt < K; kt += 32) {
#pragma unroll
    for (int i = 0; i < 2; ++i) {
      const int c = w * 2 + i;  // 8 chunks of 16 rows x 32 k each
      gl_lds16(A + (mbase + c * 16 + srow) * (long)K + kt + scol, &As[c * 512]);
      gl_lds16(B + (nbase + c * 16 + srow) * (long)K + kt + scol, &Bs[c * 512]);
    }
    __syncthreads();
    bf16x8 af[4], bfv[4];
#pragma unroll
    for (int mm = 0; mm < 4; ++mm)
      af[mm] = *(const bf16x8*)&As[(wr * 64 + mm * 16 + lr) * 32 + lg * 8];
#pragma unroll
    for (int nn = 0; nn < 4; ++nn)
      bfv[nn] = *(const bf16x8*)&Bs[(wc * 64 + nn * 16 + lr) * 32 + lg * 8];
#pragma unroll
    for (int nn = 0; nn < 4; ++nn)
#pragma unroll
      for (int mm = 0; mm < 4; ++mm)
        acc[mm][nn] = __builtin_amdgcn_mfma_f32_16x16x32_bf16(
            af[mm], bfv[nn], acc[mm][nn], 0, 0, 0);
    __syncthreads();
  }

  // Epilogue. D layout (m89-verified): col = lane&15, row = (lane>>4)*4 + r
  if constexpr (MODE == 2) {
    // transpose 128x128 tile through LDS, write [b, h, d, s] coalesced
    __shared__ __bf16 Ts[128 * 136];
#pragma unroll
    for (int mm = 0; mm < 4; ++mm)
#pragma unroll
      for (int nn = 0; nn < 4; ++nn) {
        const int d = wc * 64 + nn * 16 + lr;
#pragma unroll
        for (int r = 0; r < 4; ++r) {
          const int sl = wr * 64 + mm * 16 + lg * 4 + r;
          Ts[d * 136 + sl] = (__bf16)acc[mm][nn][r];
        }
      }
    __syncthreads();
    const long b  = mbase >> 11;
    const long s0 = mbase & 2047;
    const long h  = nbase >> 7;
    __bf16* out = (__bf16*)C;
#pragma unroll
    for (int it = 0; it < 8; ++it) {
      const int idx = it * 256 + tid;
      const int d = idx >> 4, c = idx & 15;
      bf16x8 v = *(const bf16x8*)&Ts[d * 136 + c * 8];
      *(bf16x8*)&out[((b * NHEAD + h) * HDSZ + d) * SEQ + s0 + c * 8] = v;
    }
  } else {
#pragma unroll
    for (int mm = 0; mm < 4; ++mm) {
#pragma unroll
      for (int nn = 0; nn < 4; ++nn) {
        const long n = nbase + wc * 64 + nn * 16 + lr;
#pragma unroll
        for (int r = 0; r < 4; ++r) {
          const long m = mbase + wr * 64 + mm * 16 + lg * 4 + r;
          if (MODE == 0) {
            const long b = m >> 11, s = m & 2047;
            const long h = n >> 7,  d = n & 127;
            ((__bf16*)C)[((b * NHEAD + h) * SEQ + s) * HDSZ + d] =
                (__bf16)acc[mm][nn][r];
          } else {
            ((float*)C)[m * (long)N + n] = acc[mm][nn][r];
          }
        }
      }
    }
  }
}

// ---------------- fused flash attention v2 ----------------
// grid: (SEQ/128, B*NHEAD); 4 waves; each wave owns 32 q-rows (2 row-tiles).
// K staged [64][128] and V staged from pre-transposed Vt[b,h,d,s] as [128][64],
// both via global_load_lds with XOR-swizzled source (chunk ^= row&7) so the
// b128 fragment reads are bank-conflict-free. Mask loaded direct to regs.
__global__ __launch_bounds__(256, 2) void attn_fused(
    const __bf16* __restrict__ Q, const __bf16* __restrict__ K,
    const __bf16* __restrict__ Vt, const float* __restrict__ mask,
    __bf16* __restrict__ Out) {
  __shared__ __bf16 Ks[64 * 128];   // [kcol][d], swizzled chunks
  __shared__ __bf16 Vs[128 * 64];   // [d][kcol], swizzled chunks
  __shared__ __bf16 Ps[128 * 72];   // [qrow][kcol], ld=72

  const int tid  = threadIdx.x;
  const int lane = tid & 63;
  const int w    = tid >> 6;
  const int lg   = lane >> 4, lr = lane & 15;
  const int bh   = blockIdx.y;
  const int b    = bh >> 4, h = bh & 15;
  const int q0   = blockIdx.x * 128;

  const __bf16* Qh = Q  + (size_t)bh * SEQ * HDSZ;
  const __bf16* Kh = K  + (size_t)bh * SEQ * HDSZ;
  const __bf16* Vh = Vt + (size_t)bh * HDSZ * SEQ;  // [d][s]
  const float*  Mb = mask + (size_t)b * SEQ * SEQ;

  // Q fragments: wave rows q0 + w*32 + rt*16 + lr (A-operand: row=lr, k=lg*8+i)
  bf16x8 qf[2][4];
#pragma unroll
  for (int rt = 0; rt < 2; ++rt)
#pragma unroll
    for (int kk = 0; kk < 4; ++kk)
      qf[rt][kk] = *(const bf16x8*)(
          Qh + (size_t)(q0 + w * 32 + rt * 16 + lr) * HDSZ + kk * 32 + lg * 8);

  // staging source pointers (pre-swizzled global addresses, linear LDS dest)
  const __bf16* ksrc[4];
  const __bf16* vsrc[4];
#pragma unroll
  for (int i = 0; i < 4; ++i) {
    const int krow = w * 16 + i * 4 + (lane >> 4);   // 4 rows per gl_lds
    const int kcs  = (lane & 15) ^ (krow & 7);       // 16B chunk, swizzled
    ksrc[i] = Kh + (size_t)krow * HDSZ + kcs * 8;
    const int vrow = w * 32 + i * 8 + (lane >> 3);   // 8 rows per gl_lds
    const int vcs  = (lane & 7) ^ (vrow & 7);
    vsrc[i] = Vh + (size_t)vrow * SEQ + vcs * 8;
  }

  float mrw[2][4], lrw[2][4];
#pragma unroll
  for (int rt = 0; rt < 2; ++rt)
#pragma unroll
    for (int r = 0; r < 4; ++r) { mrw[rt][r] = -1e30f; lrw[rt][r] = 0.f; }
  f32x4 acco[2][8];
#pragma unroll
  for (int rt = 0; rt < 2; ++rt)
#pragma unroll
    for (int n = 0; n < 8; ++n) acco[rt][n] = (f32x4){0.f, 0.f, 0.f, 0.f};

  for (int kt = 0; kt < SEQ; kt += 64) {
    // --- stage K [64][128] and V [128][64] via global_load_lds ---
#pragma unroll
    for (int i = 0; i < 4; ++i)
      gl_lds16(ksrc[i] + (size_t)kt * HDSZ, &Ks[(w * 16 + i * 4) * HDSZ]);
#pragma unroll
    for (int i = 0; i < 4; ++i)
      gl_lds16(vsrc[i] + kt, &Vs[(w * 32 + i * 8) * 64]);
    __syncthreads();

    // --- mask prefetch to regs (latency hides under QK MFMAs) ---
    float mk[2][4][4];
#pragma unroll
    for (int rt = 0; rt < 2; ++rt)
#pragma unroll
      for (int r = 0; r < 4; ++r) {
        const float* mp =
            Mb + (size_t)(q0 + w * 32 + rt * 16 + lg * 4 + r) * SEQ + kt + lr;
#pragma unroll
        for (int n = 0; n < 4; ++n) mk[rt][n][r] = mp[n * 16];
      }

    // --- S = Q K^T (per wave: 32 rows x 64 cols) ---
    f32x4 sacc[2][4];
#pragma unroll
    for (int rt = 0; rt < 2; ++rt)
#pragma unroll
      for (int n = 0; n < 4; ++n) sacc[rt][n] = (f32x4){0.f, 0.f, 0.f, 0.f};
#pragma unroll
    for (int n = 0; n < 4; ++n)
#pragma unroll
      for (int kk = 0; kk < 4; ++kk) {
        const int cp = (kk * 4 + lg) ^ (lr & 7);  // swizzled 16B chunk
        bf16x8 kf = *(const bf16x8*)(
            (const char*)Ks + ((n * 16 + lr) << 8) + (cp << 4));
        sacc[0][n] = __builtin_amdgcn_mfma_f32_16x16x32_bf16(qf[0][kk], kf, sacc[0][n], 0, 0, 0);
        sacc[1][n] = __builtin_amdgcn_mfma_f32_16x16x32_bf16(qf[1][kk], kf, sacc[1][n], 0, 0, 0);
      }

    // --- online softmax (rows = w*32 + rt*16 + lg*4 + r, cols over n,lr) ---
#pragma unroll
    for (int rt = 0; rt < 2; ++rt) {
      float sv[4][4], tmax[4];
#pragma unroll
      for (int r = 0; r < 4; ++r) tmax[r] = -1e30f;
#pragma unroll
      for (int n = 0; n < 4; ++n)
#pragma unroll
        for (int r = 0; r < 4; ++r) {
          float x = sacc[rt][n][r] * QK_SCALE + mk[rt][n][r];
          sv[n][r] = x;
          tmax[r] = fmaxf(tmax[r], x);
        }
#pragma unroll
      for (int r = 0; r < 4; ++r)
#pragma unroll
        for (int off = 1; off < 16; off <<= 1)
          tmax[r] = fmaxf(tmax[r], __shfl_xor(tmax[r], off));
      float corr[4];
#pragma unroll
      for (int r = 0; r < 4; ++r) {
        float mn = fmaxf(mrw[rt][r], tmax[r]);
        corr[r] = __expf(mrw[rt][r] - mn);
        mrw[rt][r] = mn;
      }
      float lsum[4] = {0.f, 0.f, 0.f, 0.f};
#pragma unroll
      for (int n = 0; n < 4; ++n)
#pragma unroll
        for (int r = 0; r < 4; ++r) {
          float p = __expf(sv[n][r] - mrw[rt][r]);
          sv[n][r] = p;
          lsum[r] += p;
        }
#pragma unroll
      for (int r = 0; r < 4; ++r) {
#pragma unroll
        for (int off = 1; off < 16; off <<= 1) lsum[r] += __shfl_xor(lsum[r], off);
        lrw[rt][r] = lrw[rt][r] * corr[r] + lsum[r];
      }
#pragma unroll
      for (int n = 0; n < 8; ++n)
#pragma unroll
        for (int r = 0; r < 4; ++r) acco[rt][n][r] *= corr[r];
      // P tile (bf16) to LDS; wave-local rows, no barrier needed
#pragma unroll
      for (int n = 0; n < 4; ++n)
#pragma unroll
        for (int r = 0; r < 4; ++r)
          Ps[(w * 32 + rt * 16 + lg * 4 + r) * 72 + n * 16 + lr] = (__bf16)sv[n][r];
    }
    __asm__ volatile("s_waitcnt lgkmcnt(0)" ::: "memory");
    __builtin_amdgcn_sched_barrier(0);

    // --- O += P V ---
#pragma unroll
    for (int kk = 0; kk < 2; ++kk) {
      bf16x8 pa0 = *(const bf16x8*)(
          (const char*)Ps + (size_t)(w * 32 + lr) * 144 + kk * 64 + lg * 16);
      bf16x8 pa1 = *(const bf16x8*)(
          (const char*)Ps + (size_t)(w * 32 + 16 + lr) * 144 + kk * 64 + lg * 16);
#pragma unroll
      for (int n = 0; n < 8; ++n) {
        const int cp = (kk * 4 + lg) ^ (lr & 7);
        bf16x8 vf = *(const bf16x8*)(
            (const char*)Vs + ((n * 16 + lr) << 7) + (cp << 4));
        acco[0][n] = __builtin_amdgcn_mfma_f32_16x16x32_bf16(pa0, vf, acco[0][n], 0, 0, 0);
        acco[1][n] = __builtin_amdgcn_mfma_f32_16x16x32_bf16(pa1, vf, acco[1][n], 0, 0, 0);
      }
    }
    __syncthreads();  // protect Ks/Vs for next tile's staging
  }

  // --- epilogue: normalize, write attn out as [b, s, h*128+d] bf16 ---
#pragma unroll
  for (int rt = 0; rt < 2; ++rt)
#pragma unroll
    for (int r = 0; r < 4; ++r) {
      const float inv = 1.0f / lrw[rt][r];
      const int srow = q0 + w * 32 + rt * 16 + lg * 4 + r;
      const size_t base = ((size_t)b * SEQ + srow) * HDIM + h * HDSZ;
#pragma unroll
      for (int n = 0; n < 8; ++n)
        Out[base + n * 16 + lr] = (__bf16)(acco[rt][n][r] * inv);
    }
}

// ---------------- launcher ----------------
extern "C" void kernel_launch(void* const* d_in, const int* in_sizes, int n_in,
                              void* d_out, int out_size, void* d_ws, size_t ws_size,
                              hipStream_t stream) {
  const float* x    = (const float*)d_in[0];
  const float* mask = (const float*)d_in[1];
  const float* wq   = (const float*)d_in[2];
  const float* wk   = (const float*)d_in[3];
  const float* wv   = (const float*)d_in[4];
  const float* wo   = (const float*)d_in[5];

  constexpr long XN = 4096L * 2048;  // 8388608
  constexpr long WN = 2048L * 2048;  // 4194304

  __bf16* xbf = (__bf16*)d_ws;
  __bf16* wqb = xbf + XN;
  __bf16* wkb = wqb + WN;
  __bf16* wvb = wkb + WN;
  __bf16* wob = wvb + WN;
  __bf16* qw  = wob + WN;
  __bf16* kw  = qw + XN;
  __bf16* vtw = kw + XN;             // V pre-transposed: [b, h, d, s]
  __bf16* aw  = vtw + XN;            // attention output [4096][2048]

  cast_f32_bf16<<<2048, 256, 0, stream>>>(x,  xbf, (int)(XN / 4));
  cast_f32_bf16<<<1024, 256, 0, stream>>>(wq, wqb, (int)(WN / 4));
  cast_f32_bf16<<<1024, 256, 0, stream>>>(wk, wkb, (int)(WN / 4));
  cast_f32_bf16<<<1024, 256, 0, stream>>>(wv, wvb, (int)(WN / 4));
  cast_f32_bf16<<<1024, 256, 0, stream>>>(wo, wob, (int)(WN / 4));

  dim3 gg(2048 / 128, 4096 / 128);  // (N-tiles, M-tiles)
  gemm_bt<0><<<gg, 256, 0, stream>>>(xbf, wqb, qw,  4096, 2048, 2048);
  gemm_bt<0><<<gg, 256, 0, stream>>>(xbf, wkb, kw,  4096, 2048, 2048);
  gemm_bt<2><<<gg, 256, 0, stream>>>(xbf, wvb, vtw, 4096, 2048, 2048);

  attn_fused<<<dim3(SEQ / 128, 2 * NHEAD), 256, 0, stream>>>(qw, kw, vtw, mask, aw);

  gemm_bt<1><<<gg, 256, 0, stream>>>(aw, wob, d_out, 4096, 2048, 2048);
}

// Round 3
// 361.305 us; speedup vs baseline: 1.2752x; 1.1510x over previous
//
#include <hip/hip_runtime.h>
#include <stdint.h>

// Problem constants
constexpr int SEQ   = 2048;
constexpr int NHEAD = 16;
constexpr int HDSZ  = 128;   // head dim
constexpr int HDIM  = 2048;  // model dim
constexpr float QK_SCALE = 0.08838834764831845f; // 1/sqrt(128)

typedef __attribute__((ext_vector_type(8))) __bf16 bf16x8;
typedef __attribute__((ext_vector_type(4))) __bf16 bf16x4;
typedef __attribute__((ext_vector_type(4))) float  f32x4;

__device__ __forceinline__ void gl_lds16(const void* gptr, void* lptr) {
  // async global->LDS, 16B/lane; LDS dst is wave-uniform base + lane*16
  __builtin_amdgcn_global_load_lds(
      (const __attribute__((address_space(1))) unsigned int*)gptr,
      (__attribute__((address_space(3))) unsigned int*)lptr, 16, 0, 0);
}

// ---------------- fp32 -> bf16 casts ----------------
__global__ __launch_bounds__(256) void cast_f32_bf16(
    const float* __restrict__ in, __bf16* __restrict__ out, int n4) {
  int i = blockIdx.x * blockDim.x + threadIdx.x;
  int stride = gridDim.x * blockDim.x;
  for (; i < n4; i += stride) {
    float4 v = ((const float4*)in)[i];
    bf16x4 o = { (__bf16)v.x, (__bf16)v.y, (__bf16)v.z, (__bf16)v.w };
    ((bf16x4*)out)[i] = o;
  }
}

// 4 weight matrices in one launch; dsts are contiguous at out + y*WN
__global__ __launch_bounds__(256) void cast4_f32_bf16(
    const float* __restrict__ w0, const float* __restrict__ w1,
    const float* __restrict__ w2, const float* __restrict__ w3,
    __bf16* __restrict__ out, int n4) {
  const int y = blockIdx.y;
  const float* src = (y == 0) ? w0 : (y == 1) ? w1 : (y == 2) ? w2 : w3;
  __bf16* dst = out + (size_t)y * (size_t)n4 * 4;
  int i = blockIdx.x * blockDim.x + threadIdx.x;
  int stride = gridDim.x * blockDim.x;
  for (; i < n4; i += stride) {
    float4 v = ((const float4*)src)[i];
    bf16x4 o = { (__bf16)v.x, (__bf16)v.y, (__bf16)v.z, (__bf16)v.w };
    ((bf16x4*)dst)[i] = o;
  }
}

// ---------------- NT GEMM: C[M,N] = A[M,K] * B[N,K]^T ----------------
// m97 structure: 128x128 tile, BK=32, 4 waves, global_load_lds(16B) staging.
// Grid is FIXED dim3(16,32) = 512 blocks; XCD-aware swizzle (512%8==0).
// MODE 0: bf16 out scattered to [b, h, s, d] (Q,K).
// MODE 1: fp32 row-major (final output).
// MODE 2: bf16 out TRANSPOSED to [b, h, d, s] (V) via LDS tile transpose.
template <int MODE>
__global__ __launch_bounds__(256) void gemm_bt(
    const __bf16* __restrict__ A, const __bf16* __restrict__ B,
    void* __restrict__ C, int M, int N, int K) {
  __shared__ __bf16 As[128 * 32];
  __shared__ __bf16 Bs[128 * 32];
  const int tid  = threadIdx.x;
  const int lane = tid & 63;
  const int w    = tid >> 6;
  const int lg   = lane >> 4, lr = lane & 15;
  const int wr   = w >> 1, wc = w & 1;
  // T1 XCD swizzle: 512 blocks -> 8 chunks of 64 (one per XCD)
  const int flat = blockIdx.y * 16 + blockIdx.x;
  const int swz  = (flat & 7) * 64 + (flat >> 3);
  const long mbase = (long)(swz >> 4) * 128;
  const long nbase = (long)(swz & 15) * 128;

  f32x4 acc[4][4];
#pragma unroll
  for (int i = 0; i < 4; ++i)
#pragma unroll
    for (int j = 0; j < 4; ++j) acc[i][j] = (f32x4){0.f, 0.f, 0.f, 0.f};

  const int srow = lane >> 2;       // row within 16-row staging chunk
  const int scol = (lane & 3) * 8;  // bf16 elem offset (16B granules)

  for (int kt = 0; kt < K; kt += 32) {
#pragma unroll
    for (int i = 0; i < 2; ++i) {
      const int c = w * 2 + i;  // 8 chunks of 16 rows x 32 k each
      gl_lds16(A + (mbase + c * 16 + srow) * (long)K + kt + scol, &As[c * 512]);
      gl_lds16(B + (nbase + c * 16 + srow) * (long)K + kt + scol, &Bs[c * 512]);
    }
    __syncthreads();
    bf16x8 af[4], bfv[4];
#pragma unroll
    for (int mm = 0; mm < 4; ++mm)
      af[mm] = *(const bf16x8*)&As[(wr * 64 + mm * 16 + lr) * 32 + lg * 8];
#pragma unroll
    for (int nn = 0; nn < 4; ++nn)
      bfv[nn] = *(const bf16x8*)&Bs[(wc * 64 + nn * 16 + lr) * 32 + lg * 8];
    __builtin_amdgcn_s_setprio(1);
#pragma unroll
    for (int nn = 0; nn < 4; ++nn)
#pragma unroll
      for (int mm = 0; mm < 4; ++mm)
        acc[mm][nn] = __builtin_amdgcn_mfma_f32_16x16x32_bf16(
            af[mm], bfv[nn], acc[mm][nn], 0, 0, 0);
    __builtin_amdgcn_s_setprio(0);
    __syncthreads();
  }

  // Epilogue. D layout (m89-verified): col = lane&15, row = (lane>>4)*4 + r
  if constexpr (MODE == 2) {
    // transpose 128x128 tile through LDS, write [b, h, d, s] coalesced
    __shared__ __bf16 Ts[128 * 136];
#pragma unroll
    for (int mm = 0; mm < 4; ++mm)
#pragma unroll
      for (int nn = 0; nn < 4; ++nn) {
        const int d = wc * 64 + nn * 16 + lr;
#pragma unroll
        for (int r = 0; r < 4; ++r) {
          const int sl = wr * 64 + mm * 16 + lg * 4 + r;
          Ts[d * 136 + sl] = (__bf16)acc[mm][nn][r];
        }
      }
    __syncthreads();
    const long b  = mbase >> 11;
    const long s0 = mbase & 2047;
    const long h  = nbase >> 7;
    __bf16* out = (__bf16*)C;
#pragma unroll
    for (int it = 0; it < 8; ++it) {
      const int idx = it * 256 + tid;
      const int d = idx >> 4, c = idx & 15;
      bf16x8 v = *(const bf16x8*)&Ts[d * 136 + c * 8];
      *(bf16x8*)&out[((b * NHEAD + h) * HDSZ + d) * SEQ + s0 + c * 8] = v;
    }
  } else {
#pragma unroll
    for (int mm = 0; mm < 4; ++mm) {
#pragma unroll
      for (int nn = 0; nn < 4; ++nn) {
        const long n = nbase + wc * 64 + nn * 16 + lr;
#pragma unroll
        for (int r = 0; r < 4; ++r) {
          const long m = mbase + wr * 64 + mm * 16 + lg * 4 + r;
          if (MODE == 0) {
            const long b = m >> 11, s = m & 2047;
            const long h = n >> 7,  d = n & 127;
            ((__bf16*)C)[((b * NHEAD + h) * SEQ + s) * HDSZ + d] =
                (__bf16)acc[mm][nn][r];
          } else {
            ((float*)C)[m * (long)N + n] = acc[mm][nn][r];
          }
        }
      }
    }
  }
}

// ---------------- fused flash attention v3 ----------------
// grid dim3(16, 32) = 512 blocks, XCD-swizzled so each head's 16 q-blocks
// share an XCD (K/V L2 reuse). 4 waves; wave owns 32 q-rows.
// K/V double-buffered (T3-lite): STAGE(t+1) issued after mask loads, drained
// only at end-of-iteration barrier -> HBM latency hidden under compute.
// P tile in swizzled [128][64] LDS (chunk ^= row&7).
__global__ __launch_bounds__(256, 2) void attn_fused(
    const __bf16* __restrict__ Q, const __bf16* __restrict__ K,
    const __bf16* __restrict__ Vt, const float* __restrict__ mask,
    __bf16* __restrict__ Out) {
  __shared__ __bf16 Ks[2 * 64 * 128];   // [buf][kcol][d], swizzled chunks
  __shared__ __bf16 Vs[2 * 128 * 64];   // [buf][d][kcol], swizzled chunks
  __shared__ __bf16 Ps[128 * 64];       // [qrow][kcol], swizzled chunks

  const int tid  = threadIdx.x;
  const int lane = tid & 63;
  const int w    = tid >> 6;
  const int lg   = lane >> 4, lr = lane & 15;
  // XCD swizzle over 512 blocks
  const int flat = blockIdx.y * 16 + blockIdx.x;
  const int swz  = (flat & 7) * 64 + (flat >> 3);
  const int bh   = swz >> 4;          // b*NHEAD + h
  const int b    = bh >> 4, h = bh & 15;
  const int q0   = (swz & 15) * 128;

  const __bf16* Qh = Q  + (size_t)bh * SEQ * HDSZ;
  const __bf16* Kh = K  + (size_t)bh * SEQ * HDSZ;
  const __bf16* Vh = Vt + (size_t)bh * HDSZ * SEQ;  // [d][s]
  const float*  Mb = mask + (size_t)b * SEQ * SEQ;

  // Q fragments: wave rows q0 + w*32 + rt*16 + lr (A-operand: row=lr, k=lg*8+i)
  bf16x8 qf[2][4];
#pragma unroll
  for (int rt = 0; rt < 2; ++rt)
#pragma unroll
    for (int kk = 0; kk < 4; ++kk)
      qf[rt][kk] = *(const bf16x8*)(
          Qh + (size_t)(q0 + w * 32 + rt * 16 + lr) * HDSZ + kk * 32 + lg * 8);

  // staging source pointers (pre-swizzled global addresses, linear LDS dest)
  const __bf16* ksrc[4];
  const __bf16* vsrc[4];
#pragma unroll
  for (int i = 0; i < 4; ++i) {
    const int krow = w * 16 + i * 4 + (lane >> 4);   // 4 rows per gl_lds
    const int kcs  = (lane & 15) ^ (krow & 7);       // 16B chunk, swizzled
    ksrc[i] = Kh + (size_t)krow * HDSZ + kcs * 8;
    const int vrow = w * 32 + i * 8 + (lane >> 3);   // 8 rows per gl_lds
    const int vcs  = (lane & 7) ^ (vrow & 7);
    vsrc[i] = Vh + (size_t)vrow * SEQ + vcs * 8;
  }

  float mrw[2][4], lrw[2][4];
#pragma unroll
  for (int rt = 0; rt < 2; ++rt)
#pragma unroll
    for (int r = 0; r < 4; ++r) { mrw[rt][r] = -1e30f; lrw[rt][r] = 0.f; }
  f32x4 acco[2][8];
#pragma unroll
  for (int rt = 0; rt < 2; ++rt)
#pragma unroll
    for (int n = 0; n < 8; ++n) acco[rt][n] = (f32x4){0.f, 0.f, 0.f, 0.f};

  // prologue: stage tile 0 into buffer 0
#pragma unroll
  for (int i = 0; i < 4; ++i)
    gl_lds16(ksrc[i], &Ks[(w * 16 + i * 4) * 128]);
#pragma unroll
  for (int i = 0; i < 4; ++i)
    gl_lds16(vsrc[i], &Vs[(w * 32 + i * 8) * 64]);
  __syncthreads();

  constexpr int NT = SEQ / 64;
  for (int t = 0; t < NT; ++t) {
    const int cur = t & 1;
    const int kt = t * 64;
    const __bf16* Kb = Ks + cur * (64 * 128);
    const __bf16* Vb = Vs + cur * (128 * 64);

    // --- (A) mask prefetch to regs FIRST (oldest vmem -> softmax's wait
    //     becomes vmcnt(8), keeping the prefetch below in flight) ---
    float mk[2][4][4];
#pragma unroll
    for (int rt = 0; rt < 2; ++rt)
#pragma unroll
      for (int r = 0; r < 4; ++r) {
        const float* mp =
            Mb + (size_t)(q0 + w * 32 + rt * 16 + lg * 4 + r) * SEQ + kt + lr;
#pragma unroll
        for (int n = 0; n < 4; ++n) mk[rt][n][r] = mp[n * 16];
      }
    __builtin_amdgcn_sched_barrier(0);

    // --- (B) STAGE tile t+1 into buf^1 (drained only at end barrier) ---
    if (t + 1 < NT) {
      const int nk = kt + 64;
      __bf16* Kn = Ks + (cur ^ 1) * (64 * 128);
      __bf16* Vn = Vs + (cur ^ 1) * (128 * 64);
#pragma unroll
      for (int i = 0; i < 4; ++i)
        gl_lds16(ksrc[i] + (size_t)nk * HDSZ, &Kn[(w * 16 + i * 4) * 128]);
#pragma unroll
      for (int i = 0; i < 4; ++i)
        gl_lds16(vsrc[i] + nk, &Vn[(w * 32 + i * 8) * 64]);
    }
    __builtin_amdgcn_sched_barrier(0);

    // --- (C) S = Q K^T (per wave: 32 rows x 64 cols) ---
    f32x4 sacc[2][4];
#pragma unroll
    for (int rt = 0; rt < 2; ++rt)
#pragma unroll
      for (int n = 0; n < 4; ++n) sacc[rt][n] = (f32x4){0.f, 0.f, 0.f, 0.f};
    __builtin_amdgcn_s_setprio(1);
#pragma unroll
    for (int n = 0; n < 4; ++n)
#pragma unroll
      for (int kk = 0; kk < 4; ++kk) {
        const int cp = (kk * 4 + lg) ^ (lr & 7);  // swizzled 16B chunk
        bf16x8 kf = *(const bf16x8*)(
            (const char*)Kb + ((n * 16 + lr) << 8) + (cp << 4));
        sacc[0][n] = __builtin_amdgcn_mfma_f32_16x16x32_bf16(qf[0][kk], kf, sacc[0][n], 0, 0, 0);
        sacc[1][n] = __builtin_amdgcn_mfma_f32_16x16x32_bf16(qf[1][kk], kf, sacc[1][n], 0, 0, 0);
      }
    __builtin_amdgcn_s_setprio(0);

    // --- (D) online softmax (rows = w*32 + rt*16 + lg*4 + r) ---
#pragma unroll
    for (int rt = 0; rt < 2; ++rt) {
      float sv[4][4], tmax[4];
#pragma unroll
      for (int r = 0; r < 4; ++r) tmax[r] = -1e30f;
#pragma unroll
      for (int n = 0; n < 4; ++n)
#pragma unroll
        for (int r = 0; r < 4; ++r) {
          float x = sacc[rt][n][r] * QK_SCALE + mk[rt][n][r];
          sv[n][r] = x;
          tmax[r] = fmaxf(tmax[r], x);
        }
#pragma unroll
      for (int r = 0; r < 4; ++r)
#pragma unroll
        for (int off = 1; off < 16; off <<= 1)
          tmax[r] = fmaxf(tmax[r], __shfl_xor(tmax[r], off));
      float corr[4];
#pragma unroll
      for (int r = 0; r < 4; ++r) {
        float mn = fmaxf(mrw[rt][r], tmax[r]);
        corr[r] = __expf(mrw[rt][r] - mn);
        mrw[rt][r] = mn;
      }
      float lsum[4] = {0.f, 0.f, 0.f, 0.f};
#pragma unroll
      for (int n = 0; n < 4; ++n)
#pragma unroll
        for (int r = 0; r < 4; ++r) {
          float p = __expf(sv[n][r] - mrw[rt][r]);
          sv[n][r] = p;
          lsum[r] += p;
        }
#pragma unroll
      for (int r = 0; r < 4; ++r) {
#pragma unroll
        for (int off = 1; off < 16; off <<= 1) lsum[r] += __shfl_xor(lsum[r], off);
        lrw[rt][r] = lrw[rt][r] * corr[r] + lsum[r];
      }
#pragma unroll
      for (int n = 0; n < 8; ++n)
#pragma unroll
        for (int r = 0; r < 4; ++r) acco[rt][n][r] *= corr[r];
      // --- (E) P tile (bf16) -> swizzled LDS; wave-local rows, no barrier ---
#pragma unroll
      for (int n = 0; n < 4; ++n)
#pragma unroll
        for (int r = 0; r < 4; ++r) {
          const int prow  = w * 32 + rt * 16 + lg * 4 + r;
          const int pbyte = (n * 32 + lr * 2) ^ (((lg * 4 + r) & 7) << 4);
          *(__bf16*)((char*)Ps + prow * 128 + pbyte) = (__bf16)sv[n][r];
        }
    }
    __asm__ volatile("s_waitcnt lgkmcnt(0)" ::: "memory");
    __builtin_amdgcn_sched_barrier(0);

    // --- (F) O += P V ---
    __builtin_amdgcn_s_setprio(1);
#pragma unroll
    for (int kk = 0; kk < 2; ++kk) {
      const int pcp = (kk * 4 + lg) ^ (lr & 7);
      bf16x8 pa0 = *(const bf16x8*)(
          (const char*)Ps + (w * 32 + lr) * 128 + (pcp << 4));
      bf16x8 pa1 = *(const bf16x8*)(
          (const char*)Ps + (w * 32 + 16 + lr) * 128 + (pcp << 4));
#pragma unroll
      for (int n = 0; n < 8; ++n) {
        const int cp = (kk * 4 + lg) ^ (lr & 7);
        bf16x8 vf = *(const bf16x8*)(
            (const char*)Vb + ((n * 16 + lr) << 7) + (cp << 4));
        acco[0][n] = __builtin_amdgcn_mfma_f32_16x16x32_bf16(pa0, vf, acco[0][n], 0, 0, 0);
        acco[1][n] = __builtin_amdgcn_mfma_f32_16x16x32_bf16(pa1, vf, acco[1][n], 0, 0, 0);
      }
    }
    __builtin_amdgcn_s_setprio(0);

    // --- (G) publish next buffer / protect current from overwrite ---
    __syncthreads();
  }

  // --- epilogue: normalize, write attn out as [b, s, h*128+d] bf16 ---
#pragma unroll
  for (int rt = 0; rt < 2; ++rt)
#pragma unroll
    for (int r = 0; r < 4; ++r) {
      const float inv = 1.0f / lrw[rt][r];
      const int srow = q0 + w * 32 + rt * 16 + lg * 4 + r;
      const size_t base = ((size_t)b * SEQ + srow) * HDIM + h * HDSZ;
#pragma unroll
      for (int n = 0; n < 8; ++n)
        Out[base + n * 16 + lr] = (__bf16)(acco[rt][n][r] * inv);
    }
}

// ---------------- launcher ----------------
extern "C" void kernel_launch(void* const* d_in, const int* in_sizes, int n_in,
                              void* d_out, int out_size, void* d_ws, size_t ws_size,
                              hipStream_t stream) {
  const float* x    = (const float*)d_in[0];
  const float* mask = (const float*)d_in[1];
  const float* wq   = (const float*)d_in[2];
  const float* wk   = (const float*)d_in[3];
  const float* wv   = (const float*)d_in[4];
  const float* wo   = (const float*)d_in[5];

  constexpr long XN = 4096L * 2048;  // 8388608
  constexpr long WN = 2048L * 2048;  // 4194304

  __bf16* xbf = (__bf16*)d_ws;
  __bf16* wqb = xbf + XN;
  __bf16* wkb = wqb + WN;
  __bf16* wvb = wkb + WN;
  __bf16* wob = wvb + WN;
  __bf16* qw  = wob + WN;
  __bf16* kw  = qw + XN;
  __bf16* vtw = kw + XN;             // V pre-transposed: [b, h, d, s]
  __bf16* aw  = vtw + XN;            // attention output [4096][2048]

  cast_f32_bf16<<<2048, 256, 0, stream>>>(x, xbf, (int)(XN / 4));
  cast4_f32_bf16<<<dim3(256, 4), 256, 0, stream>>>(wq, wk, wv, wo, wqb,
                                                   (int)(WN / 4));

  dim3 gg(16, 32);  // (N-tiles, M-tiles) — FIXED, kernel swizzles internally
  gemm_bt<0><<<gg, 256, 0, stream>>>(xbf, wqb, qw,  4096, 2048, 2048);
  gemm_bt<0><<<gg, 256, 0, stream>>>(xbf, wkb, kw,  4096, 2048, 2048);
  gemm_bt<2><<<gg, 256, 0, stream>>>(xbf, wvb, vtw, 4096, 2048, 2048);

  attn_fused<<<dim3(16, 32), 256, 0, stream>>>(qw, kw, vtw, mask, aw);

  gemm_bt<1><<<gg, 256, 0, stream>>>(aw, wob, d_out, 4096, 2048, 2048);
}